// Round 1
// baseline (500.495 us; speedup 1.0000x reference)
//
#include <hip/hip_runtime.h>
#include <hip/hip_fp16.h>

// ---------------- problem constants ----------------
#define BATCH 64
#define HH    28
#define WW2   28
#define HWPX  784          // 28*28
#define PTOT  50176        // 64*784
#define CIN   384
#define DIM   96
#define MDIM  64
#define JTOT  82944        // DIM*DIM*9
#define WSAMP 82944        // per-sample conv weights (96*864)

// ws layout (bytes)
#define XD_OFF 0u                       // P*96 f16 = 9,633,792
#define Y_OFF  9633792u                 // P*96 f16
#define WP_OFF 19267584u                // 64*82944 f16 = 10,616,832
#define HS_OFF 29884416u                // 64*64 f32
#define Z_OFF  29900800u                // 64*64 f32

typedef _Float16 h2_t __attribute__((ext_vector_type(2)));

__device__ __forceinline__ h2_t as_h2(unsigned u) {
    union { unsigned u; h2_t h; } x; x.u = u; return x.h;
}

__device__ __forceinline__ float qgelu(float v) {
    return v / (1.f + __expf(-1.702f * v));
}

__device__ __forceinline__ float dot8(uint4 a, uint4 b, float acc) {
#if __has_builtin(__builtin_amdgcn_fdot2)
    acc = __builtin_amdgcn_fdot2(as_h2(a.x), as_h2(b.x), acc, false);
    acc = __builtin_amdgcn_fdot2(as_h2(a.y), as_h2(b.y), acc, false);
    acc = __builtin_amdgcn_fdot2(as_h2(a.z), as_h2(b.z), acc, false);
    acc = __builtin_amdgcn_fdot2(as_h2(a.w), as_h2(b.w), acc, false);
#else
    const __half2* ah = reinterpret_cast<const __half2*>(&a);
    const __half2* bh = reinterpret_cast<const __half2*>(&b);
    #pragma unroll
    for (int q = 0; q < 4; ++q) {
        float2 fa = __half22float2(ah[q]);
        float2 fb = __half22float2(bh[q]);
        acc = fmaf(fa.x, fb.x, acc);
        acc = fmaf(fa.y, fb.y, acc);
    }
#endif
    return acc;
}

// ============================================================
// K1: fused meta-hidden (relu(x@Wm1+bm1), reduced over pixels into hsum)
//     + adapter down-proj (quick_gelu(x@Wd+bd) -> xd f16)
// grid (13, 64), block 256. Tile: 64 pixels x 160 outputs, K-chunk 32.
// ============================================================
__global__ __launch_bounds__(256) void k1_meta_down(
    const float* __restrict__ x, const float* __restrict__ Wm1,
    const float* __restrict__ bm1, const float* __restrict__ Wd,
    const float* __restrict__ bd, float* __restrict__ hsum,
    __half* __restrict__ xd)
{
    const int tile = blockIdx.x, b = blockIdx.y;
    const int p0 = tile * 64;
    const int npix = min(64, HWPX - p0);
    __shared__ float xs[64 * 36];      // [pix][k] padded to 36
    __shared__ float wmT[64 * 36];     // [o][k] transposed
    __shared__ float wdT[96 * 36];     // [e][k] transposed
    __shared__ float hred[64];
    const int t = threadIdx.x;
    const int tr = t >> 4, tc = t & 15;

    float acc[4][10];
    #pragma unroll
    for (int ii = 0; ii < 4; ++ii)
        #pragma unroll
        for (int oo = 0; oo < 10; ++oo) acc[ii][oo] = 0.f;

    for (int k0 = 0; k0 < CIN; k0 += 32) {
        __syncthreads();
        for (int idx = t; idx < 2048; idx += 256) {
            int i = idx >> 5, c = idx & 31;
            float v = 0.f;
            if (i < npix) v = x[(size_t)(b * HWPX + p0 + i) * CIN + k0 + c];
            xs[i * 36 + c] = v;
        }
        for (int idx = t; idx < 2048; idx += 256) {
            int r = idx >> 6, c = idx & 63;
            wmT[c * 36 + r] = Wm1[(k0 + r) * MDIM + c];
        }
        for (int idx = t; idx < 3072; idx += 256) {
            int r = idx / 96, c = idx % 96;
            wdT[c * 36 + r] = Wd[(k0 + r) * DIM + c];
        }
        __syncthreads();

        #pragma unroll 2
        for (int k = 0; k < 32; k += 4) {
            float4 a[4];
            #pragma unroll
            for (int ii = 0; ii < 4; ++ii)
                a[ii] = *(const float4*)&xs[(tr + 16 * ii) * 36 + k];
            #pragma unroll
            for (int oo = 0; oo < 4; ++oo) {
                float4 w = *(const float4*)&wmT[(tc + 16 * oo) * 36 + k];
                #pragma unroll
                for (int ii = 0; ii < 4; ++ii)
                    acc[ii][oo] += a[ii].x * w.x + a[ii].y * w.y + a[ii].z * w.z + a[ii].w * w.w;
            }
            #pragma unroll
            for (int oo = 0; oo < 6; ++oo) {
                float4 w = *(const float4*)&wdT[(tc + 16 * oo) * 36 + k];
                #pragma unroll
                for (int ii = 0; ii < 4; ++ii)
                    acc[ii][4 + oo] += a[ii].x * w.x + a[ii].y * w.y + a[ii].z * w.z + a[ii].w * w.w;
            }
        }
    }

    // ---- meta: relu + per-block reduce over pixels, accumulate to hsum ----
    if (t < 64) hred[t] = 0.f;
    __syncthreads();
    #pragma unroll
    for (int oo = 0; oo < 4; ++oo) {
        int o = tc + 16 * oo;
        float s = 0.f;
        #pragma unroll
        for (int ii = 0; ii < 4; ++ii)
            if (tr + 16 * ii < npix) s += fmaxf(acc[ii][oo] + bm1[o], 0.f);
        atomicAdd(&hred[o], s);
    }
    __syncthreads();
    if (t < 64) atomicAdd(&hsum[b * 64 + t], hred[t]);

    // ---- down-proj: bias + quick_gelu -> xd (f16) ----
    #pragma unroll
    for (int ii = 0; ii < 4; ++ii) {
        int i = tr + 16 * ii;
        if (i < npix) {
            __half* row = xd + (size_t)(b * HWPX + p0 + i) * DIM;
            #pragma unroll
            for (int oo = 0; oo < 6; ++oo) {
                int e = tc + 16 * oo;
                float v = acc[ii][4 + oo] + bd[e];
                row[e] = __float2half(qgelu(v));
            }
        }
    }
}

// ============================================================
// K2a: z[b][m] = emb[m] + (hsum[b]/784)@Wm2 + bm2[m]   (grid 16, block 256)
// ============================================================
__global__ void k2a_prompt(const float* __restrict__ hsum,
                           const float* __restrict__ Wm2,
                           const float* __restrict__ bm2,
                           const float* __restrict__ emb,
                           float* __restrict__ z)
{
    int idx = blockIdx.x * 256 + threadIdx.x;   // 4096
    int b = idx >> 6, m = idx & 63;
    float acc = 0.f;
    #pragma unroll 8
    for (int d = 0; d < 64; ++d) acc += hsum[b * 64 + d] * Wm2[d * 64 + m];
    z[idx] = emb[m] + acc * (1.f / 784.f) + bm2[m];
}

// ============================================================
// K2b: wflat[b][j] = z[b]@Wh[:,j] + bh[j], stored PERMUTED as
//      wperm[b][o][t9][i] (f16), t9 = kh*3+kw.  grid 324, block 256.
//      Wh (21 MB) is read exactly once.
// ============================================================
__global__ __launch_bounds__(256) void k2b_hyper(
    const float* __restrict__ z, const float* __restrict__ Wh,
    const float* __restrict__ bh, __half* __restrict__ wperm)
{
    __shared__ float zs[4096];
    const int t = threadIdx.x;
    for (int idx = t; idx < 4096; idx += 256) zs[idx] = z[idx];
    const int j = blockIdx.x * 256 + t;         // < 82944 exactly
    float wh[64];
    #pragma unroll 8
    for (int m = 0; m < 64; ++m) wh[m] = Wh[(size_t)m * JTOT + j];
    __syncthreads();

    const int o = j / 864, rem = j % 864;
    const int i = rem / 9, t9 = rem % 9;
    const int base = o * 864 + t9 * 96 + i;
    const float bj = bh[j];
    for (int b = 0; b < 64; ++b) {
        float a = bj;
        const float4* zz = (const float4*)(zs + b * 64);
        #pragma unroll
        for (int m4 = 0; m4 < 16; ++m4) {
            float4 v = zz[m4];
            a += v.x * wh[4 * m4] + v.y * wh[4 * m4 + 1] +
                 v.z * wh[4 * m4 + 2] + v.w * wh[4 * m4 + 3];
        }
        wperm[(size_t)b * WSAMP + base] = __float2half(a);
    }
}

// ============================================================
// K3: per-sample grouped 3x3 conv + quick_gelu.  grid (7, 64), block 256.
// Block: 4 output rows x 28 cols x all 96 out-channels of one sample.
// xd tile (6 rows w/ halo) in LDS; weights via L1-broadcast global loads.
// Thread: 7 spatial x 6 channels register tile.
// ============================================================
__global__ __launch_bounds__(256) void k3_conv(
    const __half* __restrict__ xd, const __half* __restrict__ wperm,
    __half* __restrict__ y)
{
    const int rt = blockIdx.x, b = blockIdx.y;
    const int h0 = rt * 4;
    __shared__ alignas(16) __half xt[6 * 28 * 96];   // 32256 B
    const int t = threadIdx.x;

    // stage xd rows h0-1 .. h0+4 (zero-padded)
    for (int idx = t; idx < 2016; idx += 256) {
        int e = idx * 8;
        int r = e / 2688, rr = e % 2688;   // 2688 = 28*96 halves per row
        int g = h0 - 1 + r;
        uint4 v = {0u, 0u, 0u, 0u};
        if (g >= 0 && g < HH)
            v = *(const uint4*)(xd + (size_t)(b * HWPX + g * 28) * DIM + rr);
        *(uint4*)(xt + e) = v;
    }
    __syncthreads();

    const int og = t & 15, sg = t >> 4;
    int oh_[7], ow_[7];
    #pragma unroll
    for (int si = 0; si < 7; ++si) {
        int s = sg + 16 * si;              // 0..111
        oh_[si] = s / 28; ow_[si] = s - oh_[si] * 28;
    }

    float acc[7][6];
    #pragma unroll
    for (int si = 0; si < 7; ++si)
        #pragma unroll
        for (int oj = 0; oj < 6; ++oj) acc[si][oj] = 0.f;

    const uint4* xtv = (const uint4*)xt;                       // 12 uint4 per pixel
    const uint4* wq0 = (const uint4*)(wperm + (size_t)b * WSAMP);

    for (int kh = 0; kh < 3; ++kh) {
        for (int kw = 0; kw < 3; ++kw) {
            const int t9 = kh * 3 + kw;
            int xb[7];
            #pragma unroll
            for (int si = 0; si < 7; ++si) {
                int ww = ow_[si] + kw - 1;
                xb[si] = ((unsigned)ww < 28u) ? ((oh_[si] + kh) * 28 + ww) * 12 : -1;
            }
            const uint4* wq = wq0 + t9 * 12;   // + oo*108 + i8
            #pragma unroll 3
            for (int i8 = 0; i8 < 12; ++i8) {
                uint4 wv[6];
                #pragma unroll
                for (int oj = 0; oj < 6; ++oj)
                    wv[oj] = wq[(og + 16 * oj) * 108 + i8];
                #pragma unroll
                for (int si = 0; si < 7; ++si) {
                    uint4 xv = (xb[si] >= 0) ? xtv[xb[si] + i8]
                                             : uint4{0u, 0u, 0u, 0u};
                    #pragma unroll
                    for (int oj = 0; oj < 6; ++oj)
                        acc[si][oj] = dot8(xv, wv[oj], acc[si][oj]);
                }
            }
        }
    }

    #pragma unroll
    for (int si = 0; si < 7; ++si) {
        int p = b * HWPX + (h0 + oh_[si]) * 28 + ow_[si];
        __half* yr = y + (size_t)p * DIM + og;
        #pragma unroll
        for (int oj = 0; oj < 6; ++oj)
            yr[16 * oj] = __float2half(qgelu(acc[si][oj]));
    }
}

// ============================================================
// K4: out = y @ Wu + bu.  grid 784, block 256 (64 pixels per block).
// ============================================================
__global__ __launch_bounds__(256) void k4_up(
    const __half* __restrict__ y, const float* __restrict__ Wu,
    const float* __restrict__ bu, float* __restrict__ out)
{
    const int pb = blockIdx.x;
    __shared__ float ys[64 * 96];       // 24576 B
    const int t = threadIdx.x;

    for (int idx = t; idx < 768; idx += 256) {
        uint4 v = *(const uint4*)(y + (size_t)pb * 6144 + idx * 8);
        const __half2* hv = reinterpret_cast<const __half2*>(&v);
        float* dst = ys + idx * 8;
        #pragma unroll
        for (int q = 0; q < 4; ++q) {
            float2 f = __half22float2(hv[q]);
            dst[2 * q] = f.x; dst[2 * q + 1] = f.y;
        }
    }
    __syncthreads();

    const int cl = t & 127, pr = t >> 7;
    for (int cc = 0; cc < 3; ++cc) {
        const int c = cc * 128 + cl;
        float acc[32];
        #pragma unroll
        for (int ii = 0; ii < 32; ++ii) acc[ii] = 0.f;
        for (int k = 0; k < 96; k += 4) {
            float w0 = Wu[(k + 0) * CIN + c];
            float w1 = Wu[(k + 1) * CIN + c];
            float w2 = Wu[(k + 2) * CIN + c];
            float w3 = Wu[(k + 3) * CIN + c];
            #pragma unroll
            for (int ii = 0; ii < 32; ++ii) {
                float4 yv = *(const float4*)&ys[(pr * 32 + ii) * 96 + k];
                acc[ii] = fmaf(yv.x, w0, acc[ii]);
                acc[ii] = fmaf(yv.y, w1, acc[ii]);
                acc[ii] = fmaf(yv.z, w2, acc[ii]);
                acc[ii] = fmaf(yv.w, w3, acc[ii]);
            }
        }
        const float bc = bu[c];
        #pragma unroll
        for (int ii = 0; ii < 32; ++ii) {
            int px = pr * 32 + ii;
            out[(size_t)(pb * 64 + px) * CIN + c] = acc[ii] + bc;
        }
    }
}

// ============================================================
extern "C" void kernel_launch(void* const* d_in, const int* in_sizes, int n_in,
                              void* d_out, int out_size, void* d_ws, size_t ws_size,
                              hipStream_t stream)
{
    const float* x   = (const float*)d_in[0];
    const float* Wd  = (const float*)d_in[1];
    const float* bd  = (const float*)d_in[2];
    const float* Wm1 = (const float*)d_in[3];
    const float* bm1 = (const float*)d_in[4];
    const float* Wm2 = (const float*)d_in[5];
    const float* bm2 = (const float*)d_in[6];
    const float* Wh  = (const float*)d_in[7];
    const float* bh  = (const float*)d_in[8];
    const float* emb = (const float*)d_in[9];
    const float* Wu  = (const float*)d_in[10];
    const float* bu  = (const float*)d_in[11];
    float* out = (float*)d_out;

    char* ws = (char*)d_ws;
    __half* xd    = (__half*)(ws + XD_OFF);
    __half* ybuf  = (__half*)(ws + Y_OFF);
    __half* wperm = (__half*)(ws + WP_OFF);
    float*  hsum  = (float*)(ws + HS_OFF);
    float*  z     = (float*)(ws + Z_OFF);

    hipMemsetAsync(hsum, 0, 64 * 64 * sizeof(float), stream);

    k1_meta_down<<<dim3(13, 64), 256, 0, stream>>>(x, Wm1, bm1, Wd, bd, hsum, xd);
    k2a_prompt<<<16, 256, 0, stream>>>(hsum, Wm2, bm2, emb, z);
    k2b_hyper<<<324, 256, 0, stream>>>(z, Wh, bh, wperm);
    k3_conv<<<dim3(7, 64), 256, 0, stream>>>(xd, wperm, ybuf);
    k4_up<<<784, 256, 0, stream>>>(ybuf, Wu, bu, out);
}

// Round 2
// 306.955 us; speedup vs baseline: 1.6305x; 1.6305x over previous
//
#include <hip/hip_runtime.h>
#include <hip/hip_fp16.h>

// ---------------- problem constants ----------------
#define BATCH 64
#define HH    28
#define WW2   28
#define HWPX  784          // 28*28
#define PTOT  50176        // 64*784
#define CIN   384
#define DIM   96
#define MDIM  64
#define JTOT  82944        // DIM*DIM*9
#define WSAMP 82944        // per-sample conv weights (96*864)

// ws layout (bytes)
#define XD_OFF 0u                       // P*96 f16 = 9,633,792
#define Y_OFF  9633792u                 // P*96 f16
#define WP_OFF 19267584u                // 64*82944 f16 = 10,616,832
#define HS_OFF 29884416u                // 64*64 f32
#define Z_OFF  29900800u                // 64*64 f32
// Wt (f16 [160][384] = 122,880 B) lives at WP_OFF: consumed by k1 BEFORE
// k2b overwrites the wperm region. Single stream -> deterministic.

typedef _Float16 f16x8 __attribute__((ext_vector_type(8)));
typedef _Float16 f16x4 __attribute__((ext_vector_type(4)));
typedef float f32x4 __attribute__((ext_vector_type(4)));
typedef _Float16 h2_t __attribute__((ext_vector_type(2)));

__device__ __forceinline__ h2_t as_h2(unsigned u) {
    union { unsigned u; h2_t h; } x; x.u = u; return x.h;
}

__device__ __forceinline__ float qgelu(float v) {
    return v / (1.f + __expf(-1.702f * v));
}

__device__ __forceinline__ float dot8(uint4 a, uint4 b, float acc) {
#if __has_builtin(__builtin_amdgcn_fdot2)
    acc = __builtin_amdgcn_fdot2(as_h2(a.x), as_h2(b.x), acc, false);
    acc = __builtin_amdgcn_fdot2(as_h2(a.y), as_h2(b.y), acc, false);
    acc = __builtin_amdgcn_fdot2(as_h2(a.z), as_h2(b.z), acc, false);
    acc = __builtin_amdgcn_fdot2(as_h2(a.w), as_h2(b.w), acc, false);
#else
    const __half2* ah = reinterpret_cast<const __half2*>(&a);
    const __half2* bh = reinterpret_cast<const __half2*>(&b);
    #pragma unroll
    for (int q = 0; q < 4; ++q) {
        float2 fa = __half22float2(ah[q]);
        float2 fb = __half22float2(bh[q]);
        acc = fmaf(fa.x, fb.x, acc);
        acc = fmaf(fa.y, fb.y, acc);
    }
#endif
    return acc;
}

// ============================================================
// K0: convert [Wm1 | Wd] -> Wt f16, layout [o=160][k=384]
// ============================================================
__global__ void k0_wcvt(const float* __restrict__ Wm1,
                        const float* __restrict__ Wd,
                        _Float16* __restrict__ Wt)
{
    int i = blockIdx.x * 256 + threadIdx.x;   // < 61440
    int o = i / CIN, k = i - o * CIN;
    float v = (o < MDIM) ? Wm1[k * MDIM + o] : Wd[k * DIM + (o - MDIM)];
    Wt[i] = (_Float16)v;
}

// ============================================================
// K1: MFMA GEMM  C[P,160] = f16(x)[P,384] @ Wt^T, fused epilogues:
//   cols 0..63  : relu(+bm1) -> per-sample sum -> hsum (atomics)
//   cols 64..159: quick_gelu(+bd) -> xd f16
// grid 392, block 512 (8 waves: 4m x 2n). Tile M=128, N=160, KC=32.
// ============================================================
__global__ __launch_bounds__(512, 4) void k1_mfma(
    const float* __restrict__ x, const _Float16* __restrict__ Wt,
    const float* __restrict__ bm1, const float* __restrict__ bd,
    float* __restrict__ hsum, __half* __restrict__ xd)
{
    __shared__ char smem[25088];
    _Float16* As  = (_Float16*)smem;            // [128][40] f16
    _Float16* Bs  = (_Float16*)(smem + 10240);  // [160][40] f16
    _Float16* xds = (_Float16*)smem;            // [128][96] f16 (epilogue)
    float*   hred = (float*)(smem + 24576);     // [2][64] f32

    const int t = threadIdx.x;
    const int p0 = blockIdx.x * 128;
    const int lane = t & 63, w = t >> 6;
    const int wm = w >> 1, wn = w & 1;          // 4 x 2 wave grid

    f32x4 acc[2][5];
    #pragma unroll
    for (int mf = 0; mf < 2; ++mf)
        #pragma unroll
        for (int nf = 0; nf < 5; ++nf) acc[mf][nf] = (f32x4){0.f, 0.f, 0.f, 0.f};

    // staging registers (chunk prefetch)
    float4 ra[2];
    uint4  rb0, rb1;
    const int ar0 = t >> 3, aq0 = t & 7;            // e = t
    const int ar1 = (t + 512) >> 3, aq1 = t & 7;    // e = t + 512
    const int br0 = t >> 2, bq0 = t & 3;            // e = t        (<640)
    const int br1 = (t + 512) >> 2, bq1 = t & 3;    // e = t + 512  (t<128)

    // prologue: load chunk 0
    {
        const int k0 = 0;
        ra[0] = *(const float4*)(x + (size_t)(p0 + ar0) * CIN + k0 + aq0 * 4);
        ra[1] = *(const float4*)(x + (size_t)(p0 + ar1) * CIN + k0 + aq1 * 4);
        rb0 = *(const uint4*)(Wt + br0 * CIN + k0 + bq0 * 8);
        if (t < 128) rb1 = *(const uint4*)(Wt + br1 * CIN + k0 + bq1 * 8);
    }

    for (int kc = 0; kc < 12; ++kc) {
        // ---- write staged regs to LDS (f32 -> f16 for A) ----
        #pragma unroll
        for (int i = 0; i < 2; ++i) {
            const int r = i ? ar1 : ar0, q = i ? aq1 : aq0;
            f16x4 h;
            h[0] = (_Float16)ra[i].x; h[1] = (_Float16)ra[i].y;
            h[2] = (_Float16)ra[i].z; h[3] = (_Float16)ra[i].w;
            *(f16x4*)(As + r * 40 + q * 4) = h;
        }
        *(uint4*)(Bs + br0 * 40 + bq0 * 8) = rb0;
        if (t < 128) *(uint4*)(Bs + br1 * 40 + bq1 * 8) = rb1;
        __syncthreads();

        // ---- prefetch next chunk (overlaps MFMA below) ----
        if (kc + 1 < 12) {
            const int k0 = (kc + 1) * 32;
            ra[0] = *(const float4*)(x + (size_t)(p0 + ar0) * CIN + k0 + aq0 * 4);
            ra[1] = *(const float4*)(x + (size_t)(p0 + ar1) * CIN + k0 + aq1 * 4);
            rb0 = *(const uint4*)(Wt + br0 * CIN + k0 + bq0 * 8);
            if (t < 128) rb1 = *(const uint4*)(Wt + br1 * CIN + k0 + bq1 * 8);
        }

        // ---- fragments + MFMA ----
        const int ko = (lane >> 4) * 8;
        const int rl = lane & 15;
        f16x8 av[2], bv[5];
        av[0] = *(f16x8*)(As + (wm * 32 + rl) * 40 + ko);
        av[1] = *(f16x8*)(As + (wm * 32 + 16 + rl) * 40 + ko);
        #pragma unroll
        for (int nf = 0; nf < 5; ++nf)
            bv[nf] = *(f16x8*)(Bs + (wn * 80 + nf * 16 + rl) * 40 + ko);
        #pragma unroll
        for (int mf = 0; mf < 2; ++mf)
            #pragma unroll
            for (int nf = 0; nf < 5; ++nf)
                acc[mf][nf] = __builtin_amdgcn_mfma_f32_16x16x32_f16(
                    av[mf], bv[nf], acc[mf][nf], 0, 0, 0);
        __syncthreads();
    }

    // ---- epilogue ----
    if (t < 128) hred[t] = 0.f;
    __syncthreads();

    const int s0 = p0 / HWPX, s_last = (p0 + 127) / HWPX;
    #pragma unroll
    for (int mf = 0; mf < 2; ++mf) {
        #pragma unroll
        for (int nf = 0; nf < 5; ++nf) {
            const int col = wn * 80 + nf * 16 + (lane & 15);
            #pragma unroll
            for (int j = 0; j < 4; ++j) {
                const int rl = wm * 32 + mf * 16 + (lane >> 4) * 4 + j;
                float v = acc[mf][nf][j];
                if (col < 64) {
                    v = fmaxf(v + bm1[col], 0.f);
                    int sloc = (p0 + rl) / HWPX - s0;
                    atomicAdd(&hred[sloc * 64 + col], v);
                } else {
                    int e = col - 64;
                    xds[rl * 96 + e] = (_Float16)qgelu(v + bd[e]);
                }
            }
        }
    }
    __syncthreads();

    if (t < 128) {
        int sloc = t >> 6, col = t & 63, s = s0 + sloc;
        if (s <= s_last) atomicAdd(&hsum[s * 64 + col], hred[t]);
    }
    // coalesced xd store: [128][96] f16 contiguous == global layout
    #pragma unroll
    for (int i = 0; i < 3; ++i) {
        int e = t + i * 512;   // < 1536 uint4
        *(uint4*)((__half*)xd + (size_t)p0 * 96 + e * 8) = *(uint4*)(xds + e * 8);
    }
}

// ============================================================
// K2a: z[b][m] = emb[m] + (hsum[b]/784)@Wm2 + bm2[m]   (grid 16, block 256)
// ============================================================
__global__ void k2a_prompt(const float* __restrict__ hsum,
                           const float* __restrict__ Wm2,
                           const float* __restrict__ bm2,
                           const float* __restrict__ emb,
                           float* __restrict__ z)
{
    int idx = blockIdx.x * 256 + threadIdx.x;   // 4096
    int b = idx >> 6, m = idx & 63;
    float acc = 0.f;
    #pragma unroll 8
    for (int d = 0; d < 64; ++d) acc += hsum[b * 64 + d] * Wm2[d * 64 + m];
    z[idx] = emb[m] + acc * (1.f / 784.f) + bm2[m];
}

// ============================================================
// K2b: wflat[b][j] = z[b]@Wh[:,j] + bh[j], stored PERMUTED as
//      wperm[b][o][t9][i] (f16), t9 = kh*3+kw.  grid 324, block 256.
// ============================================================
__global__ __launch_bounds__(256) void k2b_hyper(
    const float* __restrict__ z, const float* __restrict__ Wh,
    const float* __restrict__ bh, __half* __restrict__ wperm)
{
    __shared__ float zs[4096];
    const int t = threadIdx.x;
    for (int idx = t; idx < 4096; idx += 256) zs[idx] = z[idx];
    const int j = blockIdx.x * 256 + t;         // < 82944 exactly
    float wh[64];
    #pragma unroll 8
    for (int m = 0; m < 64; ++m) wh[m] = Wh[(size_t)m * JTOT + j];
    __syncthreads();

    const int o = j / 864, rem = j % 864;
    const int i = rem / 9, t9 = rem % 9;
    const int base = o * 864 + t9 * 96 + i;
    const float bj = bh[j];
    for (int b = 0; b < 64; ++b) {
        float a = bj;
        const float4* zz = (const float4*)(zs + b * 64);
        #pragma unroll
        for (int m4 = 0; m4 < 16; ++m4) {
            float4 v = zz[m4];
            a += v.x * wh[4 * m4] + v.y * wh[4 * m4 + 1] +
                 v.z * wh[4 * m4 + 2] + v.w * wh[4 * m4 + 3];
        }
        wperm[(size_t)b * WSAMP + base] = __float2half(a);
    }
}

// ============================================================
// K3: per-sample grouped 3x3 conv + quick_gelu.  grid (7, 64), block 256.
// ============================================================
__global__ __launch_bounds__(256) void k3_conv(
    const __half* __restrict__ xd, const __half* __restrict__ wperm,
    __half* __restrict__ y)
{
    const int rt = blockIdx.x, b = blockIdx.y;
    const int h0 = rt * 4;
    __shared__ alignas(16) __half xt[6 * 28 * 96];   // 32256 B
    const int t = threadIdx.x;

    for (int idx = t; idx < 2016; idx += 256) {
        int e = idx * 8;
        int r = e / 2688, rr = e % 2688;
        int g = h0 - 1 + r;
        uint4 v = {0u, 0u, 0u, 0u};
        if (g >= 0 && g < HH)
            v = *(const uint4*)(xd + (size_t)(b * HWPX + g * 28) * DIM + rr);
        *(uint4*)(xt + e) = v;
    }
    __syncthreads();

    const int og = t & 15, sg = t >> 4;
    int oh_[7], ow_[7];
    #pragma unroll
    for (int si = 0; si < 7; ++si) {
        int s = sg + 16 * si;
        oh_[si] = s / 28; ow_[si] = s - oh_[si] * 28;
    }

    float acc[7][6];
    #pragma unroll
    for (int si = 0; si < 7; ++si)
        #pragma unroll
        for (int oj = 0; oj < 6; ++oj) acc[si][oj] = 0.f;

    const uint4* xtv = (const uint4*)xt;
    const uint4* wq0 = (const uint4*)(wperm + (size_t)b * WSAMP);

    for (int kh = 0; kh < 3; ++kh) {
        for (int kw = 0; kw < 3; ++kw) {
            const int t9 = kh * 3 + kw;
            int xb[7];
            #pragma unroll
            for (int si = 0; si < 7; ++si) {
                int ww = ow_[si] + kw - 1;
                xb[si] = ((unsigned)ww < 28u) ? ((oh_[si] + kh) * 28 + ww) * 12 : -1;
            }
            const uint4* wq = wq0 + t9 * 12;
            #pragma unroll 3
            for (int i8 = 0; i8 < 12; ++i8) {
                uint4 wv[6];
                #pragma unroll
                for (int oj = 0; oj < 6; ++oj)
                    wv[oj] = wq[(og + 16 * oj) * 108 + i8];
                #pragma unroll
                for (int si = 0; si < 7; ++si) {
                    uint4 xv = (xb[si] >= 0) ? xtv[xb[si] + i8]
                                             : uint4{0u, 0u, 0u, 0u};
                    #pragma unroll
                    for (int oj = 0; oj < 6; ++oj)
                        acc[si][oj] = dot8(xv, wv[oj], acc[si][oj]);
                }
            }
        }
    }

    #pragma unroll
    for (int si = 0; si < 7; ++si) {
        int p = b * HWPX + (h0 + oh_[si]) * 28 + ow_[si];
        __half* yr = y + (size_t)p * DIM + og;
        #pragma unroll
        for (int oj = 0; oj < 6; ++oj)
            yr[16 * oj] = __float2half(qgelu(acc[si][oj]));
    }
}

// ============================================================
// K4: out = y @ Wu + bu.  grid 784, block 256 (64 pixels per block).
// ============================================================
__global__ __launch_bounds__(256) void k4_up(
    const __half* __restrict__ y, const float* __restrict__ Wu,
    const float* __restrict__ bu, float* __restrict__ out)
{
    const int pb = blockIdx.x;
    __shared__ float ys[64 * 96];
    const int t = threadIdx.x;

    for (int idx = t; idx < 768; idx += 256) {
        uint4 v = *(const uint4*)(y + (size_t)pb * 6144 + idx * 8);
        const __half2* hv = reinterpret_cast<const __half2*>(&v);
        float* dst = ys + idx * 8;
        #pragma unroll
        for (int q = 0; q < 4; ++q) {
            float2 f = __half22float2(hv[q]);
            dst[2 * q] = f.x; dst[2 * q + 1] = f.y;
        }
    }
    __syncthreads();

    const int cl = t & 127, pr = t >> 7;
    for (int cc = 0; cc < 3; ++cc) {
        const int c = cc * 128 + cl;
        float acc[32];
        #pragma unroll
        for (int ii = 0; ii < 32; ++ii) acc[ii] = 0.f;
        for (int k = 0; k < 96; k += 4) {
            float w0 = Wu[(k + 0) * CIN + c];
            float w1 = Wu[(k + 1) * CIN + c];
            float w2 = Wu[(k + 2) * CIN + c];
            float w3 = Wu[(k + 3) * CIN + c];
            #pragma unroll
            for (int ii = 0; ii < 32; ++ii) {
                float4 yv = *(const float4*)&ys[(pr * 32 + ii) * 96 + k];
                acc[ii] = fmaf(yv.x, w0, acc[ii]);
                acc[ii] = fmaf(yv.y, w1, acc[ii]);
                acc[ii] = fmaf(yv.z, w2, acc[ii]);
                acc[ii] = fmaf(yv.w, w3, acc[ii]);
            }
        }
        const float bc = bu[c];
        #pragma unroll
        for (int ii = 0; ii < 32; ++ii) {
            int px = pr * 32 + ii;
            out[(size_t)(pb * 64 + px) * CIN + c] = acc[ii] + bc;
        }
    }
}

// ============================================================
extern "C" void kernel_launch(void* const* d_in, const int* in_sizes, int n_in,
                              void* d_out, int out_size, void* d_ws, size_t ws_size,
                              hipStream_t stream)
{
    const float* x   = (const float*)d_in[0];
    const float* Wd  = (const float*)d_in[1];
    const float* bd  = (const float*)d_in[2];
    const float* Wm1 = (const float*)d_in[3];
    const float* bm1 = (const float*)d_in[4];
    const float* Wm2 = (const float*)d_in[5];
    const float* bm2 = (const float*)d_in[6];
    const float* Wh  = (const float*)d_in[7];
    const float* bh  = (const float*)d_in[8];
    const float* emb = (const float*)d_in[9];
    const float* Wu  = (const float*)d_in[10];
    const float* bu  = (const float*)d_in[11];
    float* out = (float*)d_out;

    char* ws = (char*)d_ws;
    __half*   xd    = (__half*)(ws + XD_OFF);
    __half*   ybuf  = (__half*)(ws + Y_OFF);
    __half*   wperm = (__half*)(ws + WP_OFF);
    float*    hsum  = (float*)(ws + HS_OFF);
    float*    z     = (float*)(ws + Z_OFF);
    _Float16* Wt    = (_Float16*)(ws + WP_OFF);   // transient, consumed before k2b

    hipMemsetAsync(hsum, 0, 64 * 64 * sizeof(float), stream);

    k0_wcvt<<<240, 256, 0, stream>>>(Wm1, Wd, Wt);
    k1_mfma<<<392, 512, 0, stream>>>(x, Wt, bm1, bd, hsum, xd);
    k2a_prompt<<<16, 256, 0, stream>>>(hsum, Wm2, bm2, emb, z);
    k2b_hyper<<<324, 256, 0, stream>>>(z, Wh, bh, wperm);
    k3_conv<<<dim3(7, 64), 256, 0, stream>>>(xd, wperm, ybuf);
    k4_up<<<784, 256, 0, stream>>>(ybuf, Wu, bu, out);
}

// Round 3
// 137.505 us; speedup vs baseline: 3.6398x; 2.2323x over previous
//
#include <hip/hip_runtime.h>
#include <hip/hip_fp16.h>

// ---------------- problem constants ----------------
#define BATCH 64
#define HH    28
#define WW2   28
#define HWPX  784          // 28*28
#define PTOT  50176        // 64*784
#define CIN   384
#define DIM   96
#define MDIM  64
#define JTOT  82944        // DIM*DIM*9
#define WSAMP 82944        // per-sample conv weights (96*864)

// ws layout (bytes)
#define XD_OFF 0u                       // P*96 f16 = 9,633,792
#define Y_OFF  9633792u                 // P*96 f16
#define WP_OFF 19267584u                // 64*82944 f16 = 10,616,832
#define HS_OFF 29884416u                // 64*64 f32
#define Z_OFF  29900800u                // 64*64 f32
#define WUT_OFF 29917184u               // 384*96 f16 = 73,728
// Wt (f16 [160][384] = 122,880 B) lives at WP_OFF: consumed by k1 BEFORE
// k2b overwrites the wperm region. Single stream -> deterministic.

typedef _Float16 f16x8 __attribute__((ext_vector_type(8)));
typedef _Float16 f16x4 __attribute__((ext_vector_type(4)));
typedef float f32x4 __attribute__((ext_vector_type(4)));

__device__ __forceinline__ float qgelu(float v) {
    return v / (1.f + __expf(-1.702f * v));
}

// ============================================================
// K0: convert [Wm1 | Wd] -> Wt f16 [o=160][k=384]
//     and Wu [96][384] -> WuT f16 [c=384][d=96]
// grid 384, block 256.
// ============================================================
__global__ void k0_wcvt(const float* __restrict__ Wm1,
                        const float* __restrict__ Wd,
                        const float* __restrict__ Wu,
                        _Float16* __restrict__ Wt,
                        _Float16* __restrict__ WuT)
{
    int i = blockIdx.x * 256 + threadIdx.x;   // < 98304
    if (i < 61440) {
        int o = i / CIN, k = i - o * CIN;
        float v = (o < MDIM) ? Wm1[k * MDIM + o] : Wd[k * DIM + (o - MDIM)];
        Wt[i] = (_Float16)v;
    } else {
        int j = i - 61440;                    // < 36864
        int c = j / DIM, d = j - c * DIM;
        WuT[j] = (_Float16)Wu[d * CIN + c];
    }
}

// ============================================================
// K1: MFMA GEMM  C[P,160] = f16(x)[P,384] @ Wt^T, fused epilogues:
//   cols 0..63  : relu(+bm1) -> per-sample sum -> hsum (atomics)
//   cols 64..159: quick_gelu(+bd) -> xd f16
// grid 392, block 512 (8 waves: 4m x 2n). Tile M=128, N=160, KC=32.
// ============================================================
__global__ __launch_bounds__(512, 4) void k1_mfma(
    const float* __restrict__ x, const _Float16* __restrict__ Wt,
    const float* __restrict__ bm1, const float* __restrict__ bd,
    float* __restrict__ hsum, __half* __restrict__ xd)
{
    __shared__ char smem[25088];
    _Float16* As  = (_Float16*)smem;            // [128][40] f16
    _Float16* Bs  = (_Float16*)(smem + 10240);  // [160][40] f16
    _Float16* xds = (_Float16*)smem;            // [128][96] f16 (epilogue)
    float*   hred = (float*)(smem + 24576);     // [2][64] f32

    const int t = threadIdx.x;
    const int p0 = blockIdx.x * 128;
    const int lane = t & 63, w = t >> 6;
    const int wm = w >> 1, wn = w & 1;          // 4 x 2 wave grid

    f32x4 acc[2][5];
    #pragma unroll
    for (int mf = 0; mf < 2; ++mf)
        #pragma unroll
        for (int nf = 0; nf < 5; ++nf) acc[mf][nf] = (f32x4){0.f, 0.f, 0.f, 0.f};

    float4 ra[2];
    uint4  rb0, rb1;
    const int ar0 = t >> 3, aq0 = t & 7;
    const int ar1 = (t + 512) >> 3, aq1 = t & 7;
    const int br0 = t >> 2, bq0 = t & 3;
    const int br1 = (t + 512) >> 2, bq1 = t & 3;

    {
        const int k0 = 0;
        ra[0] = *(const float4*)(x + (size_t)(p0 + ar0) * CIN + k0 + aq0 * 4);
        ra[1] = *(const float4*)(x + (size_t)(p0 + ar1) * CIN + k0 + aq1 * 4);
        rb0 = *(const uint4*)(Wt + br0 * CIN + k0 + bq0 * 8);
        if (t < 128) rb1 = *(const uint4*)(Wt + br1 * CIN + k0 + bq1 * 8);
    }

    for (int kc = 0; kc < 12; ++kc) {
        #pragma unroll
        for (int i = 0; i < 2; ++i) {
            const int r = i ? ar1 : ar0, q = i ? aq1 : aq0;
            f16x4 h;
            h[0] = (_Float16)ra[i].x; h[1] = (_Float16)ra[i].y;
            h[2] = (_Float16)ra[i].z; h[3] = (_Float16)ra[i].w;
            *(f16x4*)(As + r * 40 + q * 4) = h;
        }
        *(uint4*)(Bs + br0 * 40 + bq0 * 8) = rb0;
        if (t < 128) *(uint4*)(Bs + br1 * 40 + bq1 * 8) = rb1;
        __syncthreads();

        if (kc + 1 < 12) {
            const int k0 = (kc + 1) * 32;
            ra[0] = *(const float4*)(x + (size_t)(p0 + ar0) * CIN + k0 + aq0 * 4);
            ra[1] = *(const float4*)(x + (size_t)(p0 + ar1) * CIN + k0 + aq1 * 4);
            rb0 = *(const uint4*)(Wt + br0 * CIN + k0 + bq0 * 8);
            if (t < 128) rb1 = *(const uint4*)(Wt + br1 * CIN + k0 + bq1 * 8);
        }

        const int ko = (lane >> 4) * 8;
        const int rl = lane & 15;
        f16x8 av[2], bv[5];
        av[0] = *(f16x8*)(As + (wm * 32 + rl) * 40 + ko);
        av[1] = *(f16x8*)(As + (wm * 32 + 16 + rl) * 40 + ko);
        #pragma unroll
        for (int nf = 0; nf < 5; ++nf)
            bv[nf] = *(f16x8*)(Bs + (wn * 80 + nf * 16 + rl) * 40 + ko);
        #pragma unroll
        for (int mf = 0; mf < 2; ++mf)
            #pragma unroll
            for (int nf = 0; nf < 5; ++nf)
                acc[mf][nf] = __builtin_amdgcn_mfma_f32_16x16x32_f16(
                    av[mf], bv[nf], acc[mf][nf], 0, 0, 0);
        __syncthreads();
    }

    if (t < 128) hred[t] = 0.f;
    __syncthreads();

    const int s0 = p0 / HWPX, s_last = (p0 + 127) / HWPX;
    #pragma unroll
    for (int mf = 0; mf < 2; ++mf) {
        #pragma unroll
        for (int nf = 0; nf < 5; ++nf) {
            const int col = wn * 80 + nf * 16 + (lane & 15);
            #pragma unroll
            for (int j = 0; j < 4; ++j) {
                const int rl = wm * 32 + mf * 16 + (lane >> 4) * 4 + j;
                float v = acc[mf][nf][j];
                if (col < 64) {
                    v = fmaxf(v + bm1[col], 0.f);
                    int sloc = (p0 + rl) / HWPX - s0;
                    atomicAdd(&hred[sloc * 64 + col], v);
                } else {
                    int e = col - 64;
                    xds[rl * 96 + e] = (_Float16)qgelu(v + bd[e]);
                }
            }
        }
    }
    __syncthreads();

    if (t < 128) {
        int sloc = t >> 6, col = t & 63, s = s0 + sloc;
        if (s <= s_last) atomicAdd(&hsum[s * 64 + col], hred[t]);
    }
    #pragma unroll
    for (int i = 0; i < 3; ++i) {
        int e = t + i * 512;
        *(uint4*)((__half*)xd + (size_t)p0 * 96 + e * 8) = *(uint4*)(xds + e * 8);
    }
}

// ============================================================
// K2a: z[b][m] = emb[m] + (hsum[b]/784)@Wm2 + bm2[m]
// ============================================================
__global__ void k2a_prompt(const float* __restrict__ hsum,
                           const float* __restrict__ Wm2,
                           const float* __restrict__ bm2,
                           const float* __restrict__ emb,
                           float* __restrict__ z)
{
    int idx = blockIdx.x * 256 + threadIdx.x;   // 4096
    int b = idx >> 6, m = idx & 63;
    float acc = 0.f;
    #pragma unroll 8
    for (int d = 0; d < 64; ++d) acc += hsum[b * 64 + d] * Wm2[d * 64 + m];
    z[idx] = emb[m] + acc * (1.f / 784.f) + bm2[m];
}

// ============================================================
// K2b: wflat[b][j] = z[b]@Wh[:,j] + bh[j], stored PERMUTED as
//      wperm[b][o][t9][i] (f16).  grid 324, block 256.
// ============================================================
__global__ __launch_bounds__(256) void k2b_hyper(
    const float* __restrict__ z, const float* __restrict__ Wh,
    const float* __restrict__ bh, __half* __restrict__ wperm)
{
    __shared__ float zs[4096];
    const int t = threadIdx.x;
    for (int idx = t; idx < 4096; idx += 256) zs[idx] = z[idx];
    const int j = blockIdx.x * 256 + t;
    float wh[64];
    #pragma unroll 8
    for (int m = 0; m < 64; ++m) wh[m] = Wh[(size_t)m * JTOT + j];
    __syncthreads();

    const int o = j / 864, rem = j % 864;
    const int i = rem / 9, t9 = rem % 9;
    const int base = o * 864 + t9 * 96 + i;
    const float bj = bh[j];
    for (int b = 0; b < 64; ++b) {
        float a = bj;
        const float4* zz = (const float4*)(zs + b * 64);
        #pragma unroll
        for (int m4 = 0; m4 < 16; ++m4) {
            float4 v = zz[m4];
            a += v.x * wh[4 * m4] + v.y * wh[4 * m4 + 1] +
                 v.z * wh[4 * m4 + 2] + v.w * wh[4 * m4 + 3];
        }
        wperm[(size_t)b * WSAMP + base] = __float2half(a);
    }
}

// ============================================================
// K3: MFMA implicit-GEMM grouped 3x3 conv + quick_gelu.
// grid 448 (XCD-grouped swizzle: sample-major per XCD), block 256 (4 waves).
// Block: sample b, 4 output rows (112 px = 7 m-frags), N=96 (6 n-frags).
// Waves 2m x 2n; wm1 has a phantom mf (zero-masked).  K = 864 = 9 t9 * 3.
// A: xd tile in LDS, pixel stride 104 halves; OOB lanes read a zero block.
// B: wperm fragments direct from global (L1/L2-resident per sample).
// ============================================================
__global__ __launch_bounds__(256) void k3_mfma(
    const __half* __restrict__ xd, const __half* __restrict__ wperm,
    __half* __restrict__ y)
{
    __shared__ __half sm[17600];                 // 35,200 B
    const int t = threadIdx.x;

    const int n = blockIdx.x;                    // 448
    const int xcd = n & 7, jj0 = n >> 3;         // jj0 < 56
    const int b = xcd * 8 + jj0 / 7;
    const int rt = jj0 % 7;
    const int h0 = rt * 4;

    if (t < 16) *(uint4*)(sm + 17472 + t * 8) = uint4{0u, 0u, 0u, 0u};
    for (int idx = t; idx < 2016; idx += 256) {
        int pix = idx / 12, q = idx - pix * 12;
        int r = pix / 28, col = pix - r * 28;
        int g = h0 - 1 + r;
        uint4 v = {0u, 0u, 0u, 0u};
        if ((unsigned)g < 28u)
            v = *(const uint4*)(xd + (size_t)(b * HWPX + g * 28 + col) * 96 + q * 8);
        *(uint4*)(sm + pix * 104 + q * 8) = v;
    }
    __syncthreads();

    const int lane = t & 63, w = t >> 6;
    const int wm = w >> 1, wn = w & 1;
    const int mloc = lane & 15, klo = (lane >> 4) * 8;
    const int base_m = wm * 64;

    int oh_[4], ow_[4]; bool pv[4];
    #pragma unroll
    for (int mf = 0; mf < 4; ++mf) {
        int p = base_m + mf * 16 + mloc;
        pv[mf] = (p < 112);
        int pp = pv[mf] ? p : 0;
        oh_[mf] = pp / 28; ow_[mf] = pp - oh_[mf] * 28;
    }
    const __half* wp = wperm + (size_t)b * WSAMP + (wn * 48 + mloc) * 864 + klo;

    f32x4 acc[4][3];
    #pragma unroll
    for (int mf = 0; mf < 4; ++mf)
        #pragma unroll
        for (int nf = 0; nf < 3; ++nf) acc[mf][nf] = (f32x4){0.f, 0.f, 0.f, 0.f};

    #pragma unroll
    for (int kh = 0; kh < 3; ++kh) {
        #pragma unroll
        for (int kw = 0; kw < 3; ++kw) {
            const int t9 = kh * 3 + kw;
            int abase[4];
            #pragma unroll
            for (int mf = 0; mf < 4; ++mf) {
                int iw = ow_[mf] + kw - 1;
                bool valid = pv[mf] && ((unsigned)iw < 28u);
                abase[mf] = valid ? ((oh_[mf] + kh) * 28 + iw) * 104 + klo
                                  : 17472 + klo;
            }
            #pragma unroll
            for (int ic = 0; ic < 3; ++ic) {
                f16x8 av[4], bv[3];
                #pragma unroll
                for (int nf = 0; nf < 3; ++nf)
                    bv[nf] = *(const f16x8*)(wp + nf * 13824 + t9 * 96 + ic * 32);
                #pragma unroll
                for (int mf = 0; mf < 4; ++mf)
                    av[mf] = *(const f16x8*)(sm + abase[mf] + ic * 32);
                #pragma unroll
                for (int mf = 0; mf < 4; ++mf)
                    #pragma unroll
                    for (int nf = 0; nf < 3; ++nf)
                        acc[mf][nf] = __builtin_amdgcn_mfma_f32_16x16x32_f16(
                            av[mf], bv[nf], acc[mf][nf], 0, 0, 0);
            }
        }
    }
    __syncthreads();

    // repack (f16 + qgelu) into LDS, then contiguous global store
    #pragma unroll
    for (int mf = 0; mf < 4; ++mf) {
        #pragma unroll
        for (int nf = 0; nf < 3; ++nf) {
            const int o = wn * 48 + nf * 16 + mloc;
            #pragma unroll
            for (int j = 0; j < 4; ++j) {
                int p = base_m + mf * 16 + (lane >> 4) * 4 + j;
                if (p < 112)
                    sm[p * 104 + o] = __float2half(qgelu(acc[mf][nf][j]));
            }
        }
    }
    __syncthreads();
    for (int idx = t; idx < 1344; idx += 256) {
        int pix = idx / 12, q = idx - pix * 12;
        *(uint4*)(y + (size_t)(b * HWPX + h0 * 28 + pix) * 96 + q * 8) =
            *(uint4*)(sm + pix * 104 + q * 8);
    }
}

// ============================================================
// K4: MFMA GEMM  out[P,384] = y[P,96] @ Wu + bu (f32 out).
// grid 392, block 512 (8 waves 2m x 4n). Tile M=128, N=384, K=96.
// A: y tile in LDS (stride 104). B: WuT fragments direct global.
// ============================================================
__global__ __launch_bounds__(512, 2) void k4_mfma(
    const __half* __restrict__ y, const _Float16* __restrict__ WuT,
    const float* __restrict__ bu, float* __restrict__ out)
{
    __shared__ __half ys[128 * 104];             // 26,624 B
    const int t = threadIdx.x;
    const int p0 = blockIdx.x * 128;

    #pragma unroll
    for (int i = 0; i < 3; ++i) {
        int idx = t + i * 512;                   // < 1536
        int pix = idx / 12, q = idx - pix * 12;
        *(uint4*)(ys + pix * 104 + q * 8) =
            *(const uint4*)(y + (size_t)(p0 + pix) * 96 + q * 8);
    }

    const int lane = t & 63, w = t >> 6;
    const int wm = w >> 2, wn = w & 3;           // 2m x 4n
    const int mloc = lane & 15, klo = (lane >> 4) * 8;

    float bcol[6];
    #pragma unroll
    for (int nf = 0; nf < 6; ++nf) bcol[nf] = bu[wn * 96 + nf * 16 + mloc];
    __syncthreads();

    f32x4 acc[4][6];
    #pragma unroll
    for (int mf = 0; mf < 4; ++mf)
        #pragma unroll
        for (int nf = 0; nf < 6; ++nf) acc[mf][nf] = (f32x4){0.f, 0.f, 0.f, 0.f};

    #pragma unroll
    for (int kc = 0; kc < 3; ++kc) {
        f16x8 av[4], bv[6];
        #pragma unroll
        for (int nf = 0; nf < 6; ++nf)
            bv[nf] = *(const f16x8*)(WuT + (wn * 96 + nf * 16 + mloc) * 96 + kc * 32 + klo);
        #pragma unroll
        for (int mf = 0; mf < 4; ++mf)
            av[mf] = *(const f16x8*)(ys + (wm * 64 + mf * 16 + mloc) * 104 + kc * 32 + klo);
        #pragma unroll
        for (int mf = 0; mf < 4; ++mf)
            #pragma unroll
            for (int nf = 0; nf < 6; ++nf)
                acc[mf][nf] = __builtin_amdgcn_mfma_f32_16x16x32_f16(
                    av[mf], bv[nf], acc[mf][nf], 0, 0, 0);
    }

    #pragma unroll
    for (int mf = 0; mf < 4; ++mf) {
        #pragma unroll
        for (int nf = 0; nf < 6; ++nf) {
            const int c = wn * 96 + nf * 16 + mloc;
            #pragma unroll
            for (int j = 0; j < 4; ++j) {
                int p = p0 + wm * 64 + mf * 16 + (lane >> 4) * 4 + j;
                out[(size_t)p * CIN + c] = acc[mf][nf][j] + bcol[nf];
            }
        }
    }
}

// ============================================================
extern "C" void kernel_launch(void* const* d_in, const int* in_sizes, int n_in,
                              void* d_out, int out_size, void* d_ws, size_t ws_size,
                              hipStream_t stream)
{
    const float* x   = (const float*)d_in[0];
    const float* Wd  = (const float*)d_in[1];
    const float* bd  = (const float*)d_in[2];
    const float* Wm1 = (const float*)d_in[3];
    const float* bm1 = (const float*)d_in[4];
    const float* Wm2 = (const float*)d_in[5];
    const float* bm2 = (const float*)d_in[6];
    const float* Wh  = (const float*)d_in[7];
    const float* bh  = (const float*)d_in[8];
    const float* emb = (const float*)d_in[9];
    const float* Wu  = (const float*)d_in[10];
    const float* bu  = (const float*)d_in[11];
    float* out = (float*)d_out;

    char* ws = (char*)d_ws;
    __half*   xd    = (__half*)(ws + XD_OFF);
    __half*   ybuf  = (__half*)(ws + Y_OFF);
    __half*   wperm = (__half*)(ws + WP_OFF);
    float*    hsum  = (float*)(ws + HS_OFF);
    float*    z     = (float*)(ws + Z_OFF);
    _Float16* Wt    = (_Float16*)(ws + WP_OFF);   // transient, consumed before k2b
    _Float16* WuT   = (_Float16*)(ws + WUT_OFF);

    hipMemsetAsync(hsum, 0, 64 * 64 * sizeof(float), stream);

    k0_wcvt<<<384, 256, 0, stream>>>(Wm1, Wd, Wu, Wt, WuT);
    k1_mfma<<<392, 512, 0, stream>>>(x, Wt, bm1, bd, hsum, xd);
    k2a_prompt<<<16, 256, 0, stream>>>(hsum, Wm2, bm2, emb, z);
    k2b_hyper<<<324, 256, 0, stream>>>(z, Wh, bh, wperm);
    k3_mfma<<<448, 256, 0, stream>>>(xd, wperm, ybuf);
    k4_mfma<<<392, 512, 0, stream>>>(ybuf, WuT, bu, out);
}